// Round 2
// baseline (9083.443 us; speedup 1.0000x reference)
//
#include <hip/hip_runtime.h>
#include <math.h>

#define Bsz 32
#define Ssz 512
#define Hsz 1024

typedef _Float16 f16x8 __attribute__((ext_vector_type(8)));
typedef float    f32x4 __attribute__((ext_vector_type(4)));
typedef float    f32x8 __attribute__((ext_vector_type(8)));

struct P {
  const float *x, *Wx0, *Wh0, *bx0, *bh0, *Wx1, *Wh1, *bx1, *bh1;
  unsigned short *h0r;    // [4 slot][128 koct][32 b][2 plane][8] f16 frag-layout ring
  unsigned short *h1r;    // [2 slot][...]
  unsigned *f0, *f1;      // per-producer epoch flags: f0[4][64], f1[2][64]
  _Float16 *wsw;          // swizzled fp16 weights [2][64 blk][64 ks][4 m][64 lane][8]
  float *out;
};

// fp32 weights -> fp16, swizzled to exact MFMA A-frag order.
// idx bits: lane[0:5] m[6:7] ks[8:13] blk[14:19] layer[20]
__global__ __launch_bounds__(256) void preconv(P p) {
  unsigned idx   = blockIdx.x * 256 + threadIdx.x;        // < 2^21
  unsigned lane  = idx & 63;
  unsigned m     = (idx >> 6) & 3;
  unsigned ks    = (idx >> 8) & 63;
  unsigned blk   = (idx >> 14) & 63;
  unsigned layer = idx >> 20;
  unsigned hidx  = blk * 16 + (lane & 15);
  unsigned k     = ks * 32 + (lane >> 4) * 8;
  unsigned row   = m * 1024 + hidx;
  const float* src;
  if (layer == 0) src = (k < 1024) ? p.Wx0 + (size_t)row * 1024 + k
                                   : p.Wh0 + (size_t)row * 1024 + (k - 1024);
  else            src = (k < 1024) ? p.Wx1 + (size_t)row * 1024 + k
                                   : p.Wh1 + (size_t)row * 1024 + (k - 1024);
  f32x8 v = *reinterpret_cast<const f32x8*>(src);
  f16x8 h;
#pragma unroll
  for (int j = 0; j < 8; ++j) h[j] = (_Float16)v[j];
  *reinterpret_cast<f16x8*>(p.wsw + (size_t)idx * 8) = h;
}

__device__ inline void load_xfrag(const float* xp, f16x8& Bh, f16x8& Bl) {
  f32x8 v = *reinterpret_cast<const f32x8*>(xp);
#pragma unroll
  for (int j = 0; j < 8; ++j) {
    _Float16 hv = (_Float16)v[j];
    Bh[j] = hv; Bl[j] = (_Float16)(v[j] - (float)hv);
  }
}

// Persistent pipelined LSTM. 128 blocks x 512 thr, weights resident in AGPR/VGPR.
// h-ring in MFMA B-frag layout; producers store agent-scope (MALL), consumers
// acquire-fence (buffer_inv) then read via plain L2-cached 16B loads.
__global__ __launch_bounds__(512, 2) void lstm_persist(P p) {
  const int blk   = blockIdx.x;
  const int layer = blk >> 6;
  const int hb    = blk & 63;
  const int tid   = threadIdx.x;
  const int w     = tid >> 6;
  const int lane  = tid & 63;
  const int nl    = lane & 15;
  const int quad  = lane >> 4;

  __shared__ float red[8][64 * 33];   // 67.6KB: one dump slab per wave
  __shared__ float csl[Bsz * 16];     // c state [b][hl]
  __shared__ float bsum[64];          // bx+bh  [gate*16+hl]

  if (tid < 64) {
    int r = (tid >> 4) * 1024 + hb * 16 + (tid & 15);
    bsum[tid] = layer ? (p.bx1[r] + p.bh1[r]) : (p.bx0[r] + p.bh0[r]);
  }
  csl[tid] = 0.f;
  __syncthreads();

  // ---- weights: 32 frags = 128 regs per lane, loaded once ----
  const _Float16* wslab = p.wsw + (size_t)(layer * 64 + hb) * 131072;
  f16x8 Wr[32];
#pragma unroll
  for (int kk = 0; kk < 8; ++kk)
#pragma unroll
    for (int m = 0; m < 4; ++m)
      Wr[kk * 4 + m] = *reinterpret_cast<const f16x8*>(
          wslab + (size_t)(((w * 8 + kk) * 4 + m) * 64 + lane) * 8);

  const bool xwave = (layer == 0) && (w < 4);
  const int  kloc  = (w & 3) * 256;   // k-dim slab base for this wave

  for (int s = 0; s < Ssz; ++s) {
    // ---- per-wave flag polls (relaxed): each lane spins on one producer ----
    if (layer == 0) {
      if (xwave) {
        if (s >= 4) {   // h0r slot (s&3) reuse: layer-1 must have finished s-4
          const unsigned* fp = p.f1 + (s & 1) * 64 + lane;
          unsigned need = (unsigned)(s - 3);
          while (__hip_atomic_load(fp, __ATOMIC_RELAXED, __HIP_MEMORY_SCOPE_AGENT) < need) {}
        }
      } else if (s >= 1) {  // own-slab layer-0 producers finished s-1
        const unsigned* fp = p.f0 + ((s - 1) & 3) * 64 + (w & 3) * 16 + nl;
        unsigned need = (unsigned)s;
        while (__hip_atomic_load(fp, __ATOMIC_RELAXED, __HIP_MEMORY_SCOPE_AGENT) < need) {}
      }
    } else {
      if (w < 4) {           // layer-0 slab producers finished s
        const unsigned* fp = p.f0 + (s & 3) * 64 + (w & 3) * 16 + nl;
        unsigned need = (unsigned)(s + 1);
        while (__hip_atomic_load(fp, __ATOMIC_RELAXED, __HIP_MEMORY_SCOPE_AGENT) < need) {}
      } else if (s >= 1) {   // own-slab layer-1 producers finished s-1
        const unsigned* fp = p.f1 + ((s - 1) & 1) * 64 + (w & 3) * 16 + nl;
        unsigned need = (unsigned)s;
        while (__hip_atomic_load(fp, __ATOMIC_RELAXED, __HIP_MEMORY_SCOPE_AGENT) < need) {}
      }
    }

    f32x4 acc[4][2];
#pragma unroll
    for (int m = 0; m < 4; ++m)
#pragma unroll
      for (int nt = 0; nt < 2; ++nt) acc[m][nt] = (f32x4){0.f, 0.f, 0.f, 0.f};

    if (xwave) {
      // ---- x path: normal cached loads, double-buffered (unchanged) ----
      const float* xbase = p.x + (size_t)s * 1024 + kloc;
      f16x8 Bh[2][2], Bl[2][2];
      load_xfrag(xbase + (size_t)nl        * (Ssz * 1024) + quad * 8, Bh[0][0], Bl[0][0]);
      load_xfrag(xbase + (size_t)(nl + 16) * (Ssz * 1024) + quad * 8, Bh[0][1], Bl[0][1]);
#pragma unroll
      for (int kk = 0; kk < 8; ++kk) {
        const int cur = kk & 1, nxt = cur ^ 1;
        if (kk < 7) {
          const int ko = (kk + 1) * 32 + quad * 8;
          load_xfrag(xbase + (size_t)nl        * (Ssz * 1024) + ko, Bh[nxt][0], Bl[nxt][0]);
          load_xfrag(xbase + (size_t)(nl + 16) * (Ssz * 1024) + ko, Bh[nxt][1], Bl[nxt][1]);
        }
#pragma unroll
        for (int m = 0; m < 4; ++m) {
          f16x8 A = Wr[kk * 4 + m];
#pragma unroll
          for (int nt = 0; nt < 2; ++nt) {
            acc[m][nt] = __builtin_amdgcn_mfma_f32_16x16x32_f16(A, Bh[cur][nt], acc[m][nt], 0, 0, 0);
            acc[m][nt] = __builtin_amdgcn_mfma_f32_16x16x32_f16(A, Bl[cur][nt], acc[m][nt], 0, 0, 0);
          }
        }
      }
    } else {
      // ---- h path: acquire fence (invalidate stale L1/L2), then plain
      //      cached 16B fragment loads straight into MFMA operands ----
      __builtin_amdgcn_fence(__ATOMIC_ACQUIRE, "agent");
      const unsigned short* rbase;
      if (layer == 0) rbase = p.h0r + ((s - 1) & 3) * 65536;
      else if (w < 4) rbase = p.h0r + (s & 3) * 65536;
      else            rbase = p.h1r + ((s - 1) & 1) * 65536;
      // frag addr (u16): koct*512 + b*16 + plane*8 + j ; koct = kloc/8 + kk*4 + quad
      const _Float16* fb = (const _Float16*)rbase + ((w & 3) * 32 + quad) * 512 + nl * 16;
#pragma unroll
      for (int kk = 0; kk < 8; ++kk) {
        const _Float16* fp2 = fb + kk * 2048;
        f16x8 Bh0 = *reinterpret_cast<const f16x8*>(fp2);        // b=nl,    hi
        f16x8 Bl0 = *reinterpret_cast<const f16x8*>(fp2 + 8);    // b=nl,    lo
        f16x8 Bh1 = *reinterpret_cast<const f16x8*>(fp2 + 256);  // b=nl+16, hi
        f16x8 Bl1 = *reinterpret_cast<const f16x8*>(fp2 + 264);  // b=nl+16, lo
#pragma unroll
        for (int m = 0; m < 4; ++m) {
          f16x8 A = Wr[kk * 4 + m];
          acc[m][0] = __builtin_amdgcn_mfma_f32_16x16x32_f16(A, Bh0, acc[m][0], 0, 0, 0);
          acc[m][0] = __builtin_amdgcn_mfma_f32_16x16x32_f16(A, Bl0, acc[m][0], 0, 0, 0);
          acc[m][1] = __builtin_amdgcn_mfma_f32_16x16x32_f16(A, Bh1, acc[m][1], 0, 0, 0);
          acc[m][1] = __builtin_amdgcn_mfma_f32_16x16x32_f16(A, Bl1, acc[m][1], 0, 0, 0);
        }
      }
    }

    // ---- reduce: dump all 8 waves, parallel 8-way sum into slab 0 ----
    // D layout: row quad*4+reg = h-local, col nl = batch
#pragma unroll
    for (int m = 0; m < 4; ++m)
#pragma unroll
      for (int nt = 0; nt < 2; ++nt)
#pragma unroll
        for (int r = 0; r < 4; ++r)
          red[w][(m * 16 + quad * 4 + r) * 33 + nt * 16 + nl] = acc[m][nt][r];
    __syncthreads();
#pragma unroll
    for (int j = 0; j < 4; ++j) {
      int idx = tid + j * 512;
      int ad = (idx >> 5) * 33 + (idx & 31);
      float ssum = red[0][ad] + red[1][ad] + red[2][ad] + red[3][ad]
                 + red[4][ad] + red[5][ad] + red[6][ad] + red[7][ad];
      red[0][ad] = ssum;
    }
    __syncthreads();

    // ---- pointwise: tid -> hl = tid&15, b = tid>>4 ----
    {
      int hl = tid & 15, b = tid >> 4;
      float gf = red[0][(0 * 16 + hl) * 33 + b] + bsum[0 * 16 + hl];
      float gi = red[0][(1 * 16 + hl) * 33 + b] + bsum[1 * 16 + hl];
      float gg = red[0][(2 * 16 + hl) * 33 + b] + bsum[2 * 16 + hl];
      float go = red[0][(3 * 16 + hl) * 33 + b] + bsum[3 * 16 + hl];
      float f  = 1.f / (1.f + __expf(-gf));
      float i  = 1.f / (1.f + __expf(-gi));
      float g  = tanhf(gg);
      float o  = 1.f / (1.f + __expf(-go));
      float c  = f * csl[b * 16 + hl] + i * g;
      float hn = o * tanhf(c);
      csl[b * 16 + hl] = c;
      _Float16 hh  = (_Float16)hn;
      _Float16 hlo = (_Float16)(hn - (float)hh);
      unsigned short hbits = __builtin_bit_cast(unsigned short, hh);
      unsigned short lbits = __builtin_bit_cast(unsigned short, hlo);
      int hg   = hb * 16 + hl;
      int koct = hb * 2 + (hl >> 3), jj = hl & 7;
      int fragoff = koct * 512 + b * 16 + jj;
      if (layer == 0) {
        unsigned short* dst = p.h0r + (s & 3) * 65536 + fragoff;
        __hip_atomic_store(dst,     hbits, __ATOMIC_RELAXED, __HIP_MEMORY_SCOPE_AGENT);
        __hip_atomic_store(dst + 8, lbits, __ATOMIC_RELAXED, __HIP_MEMORY_SCOPE_AGENT);
      } else {
        unsigned short* dst = p.h1r + (s & 1) * 65536 + fragoff;
        __hip_atomic_store(dst,     hbits, __ATOMIC_RELAXED, __HIP_MEMORY_SCOPE_AGENT);
        __hip_atomic_store(dst + 8, lbits, __ATOMIC_RELAXED, __HIP_MEMORY_SCOPE_AGENT);
        p.out[(size_t)b * (Ssz * Hsz) + (size_t)s * Hsz + hg] = hn;
      }
      if (s == Ssz - 1) {
        float* tail = p.out + (size_t)Bsz * Ssz * Hsz;
        tail[layer * 32768 + b * 1024 + hg] = hn;            // h_n
        tail[65536 + layer * 32768 + b * 1024 + hg] = c;     // c_n
      }
    }
    __syncthreads();   // drains every wave's agent-scope stores (vmcnt(0) before barrier)
    // single plain agent-scope store; no RMW, ordered after drained h stores
    if (tid == 0) {
      if (layer == 0)
        __hip_atomic_store(p.f0 + (s & 3) * 64 + hb, (unsigned)(s + 1),
                           __ATOMIC_RELAXED, __HIP_MEMORY_SCOPE_AGENT);
      else
        __hip_atomic_store(p.f1 + (s & 1) * 64 + hb, (unsigned)(s + 1),
                           __ATOMIC_RELAXED, __HIP_MEMORY_SCOPE_AGENT);
    }
  }
}

extern "C" void kernel_launch(void* const* d_in, const int* in_sizes, int n_in,
                              void* d_out, int out_size, void* d_ws, size_t ws_size,
                              hipStream_t stream) {
  char* ws = (char*)d_ws;
  P p;
  p.x   = (const float*)d_in[0];
  p.Wx0 = (const float*)d_in[1]; p.Wh0 = (const float*)d_in[2];
  p.bx0 = (const float*)d_in[3]; p.bh0 = (const float*)d_in[4];
  p.Wx1 = (const float*)d_in[5]; p.Wh1 = (const float*)d_in[6];
  p.bx1 = (const float*)d_in[7]; p.bh1 = (const float*)d_in[8];

  p.h0r = (unsigned short*)(ws);                  // 4*65536*2B = 512KB
  p.h1r = (unsigned short*)(ws + 524288);         // 2*65536*2B = 256KB
  p.f0  = (unsigned*)(ws + 786432);               // 4*64*4B = 1KB
  p.f1  = (unsigned*)(ws + 788480);               // 2*64*4B = 512B
  p.wsw = (_Float16*)(ws + 1048576);              // 32MB
  p.out = (float*)d_out;

  // zero rings + flags (ws poisoned 0xAA each call; flags MUST start 0,
  // ring slot -1 reads must see h=0)
  hipMemsetAsync(d_ws, 0, 1048576, stream);
  preconv<<<dim3(8192), dim3(256), 0, stream>>>(p);
  lstm_persist<<<dim3(128), dim3(512), 0, stream>>>(p);
}

// Round 3
// 9017.147 us; speedup vs baseline: 1.0074x; 1.0074x over previous
//
#include <hip/hip_runtime.h>
#include <math.h>

#define Bsz 32
#define Ssz 512
#define Hsz 1024

typedef _Float16 f16x8 __attribute__((ext_vector_type(8)));
typedef float    f32x4 __attribute__((ext_vector_type(4)));
typedef float    f32x8 __attribute__((ext_vector_type(8)));

struct P {
  const float *x, *Wx0, *Wh0, *bx0, *bh0, *Wx1, *Wh1, *bx1, *bh1;
  unsigned short *h0r;    // [4 slot][128 koct][32 b][2 plane][8] f16 frag-layout ring
  unsigned short *h1r;    // [2 slot][...]
  unsigned *f0, *f1;      // per-producer epoch flags: f0[4][64], f1[2][64]
  unsigned *done;         // heater exit flag
  _Float16 *wsw;          // swizzled fp16 weights [2][64 blk][64 ks][4 m][64 lane][8]
  float *out;
};

// fp32 weights -> fp16, swizzled to exact MFMA A-frag order.
// idx bits: lane[0:5] m[6:7] ks[8:13] blk[14:19] layer[20]
__global__ __launch_bounds__(256) void preconv(P p) {
  unsigned idx   = blockIdx.x * 256 + threadIdx.x;        // < 2^21
  unsigned lane  = idx & 63;
  unsigned m     = (idx >> 6) & 3;
  unsigned ks    = (idx >> 8) & 63;
  unsigned blk   = (idx >> 14) & 63;
  unsigned layer = idx >> 20;
  unsigned hidx  = blk * 16 + (lane & 15);
  unsigned k     = ks * 32 + (lane >> 4) * 8;
  unsigned row   = m * 1024 + hidx;
  const float* src;
  if (layer == 0) src = (k < 1024) ? p.Wx0 + (size_t)row * 1024 + k
                                   : p.Wh0 + (size_t)row * 1024 + (k - 1024);
  else            src = (k < 1024) ? p.Wx1 + (size_t)row * 1024 + k
                                   : p.Wh1 + (size_t)row * 1024 + (k - 1024);
  f32x8 v = *reinterpret_cast<const f32x8*>(src);
  f16x8 h;
#pragma unroll
  for (int j = 0; j < 8; ++j) h[j] = (_Float16)v[j];
  *reinterpret_cast<f16x8*>(p.wsw + (size_t)idx * 8) = h;
}

__device__ inline void load_xfrag(const float* xp, f16x8& Bh, f16x8& Bl) {
  f32x8 v = *reinterpret_cast<const f32x8*>(xp);
#pragma unroll
  for (int j = 0; j < 8; ++j) {
    _Float16 hv = (_Float16)v[j];
    Bh[j] = hv; Bl[j] = (_Float16)(v[j] - (float)hv);
  }
}

// Persistent pipelined LSTM (blocks 0-127) + DVFS heater blocks (128-255).
// LSTM logic identical to round 2; heaters keep the other 128 CUs busy so
// the clock governor holds high SCLK during the latency-bound recurrence.
__global__ __launch_bounds__(512, 2) void lstm_persist(P p) {
  const int blk   = blockIdx.x;
  const int tid   = threadIdx.x;

  if (blk >= 128) {
    // ---- heater: dense independent FMA chains, poll done every ~2k cycles ----
    float a0 = 1.f + tid, a1 = 2.f + tid, a2 = 3.f + tid, a3 = 4.f + tid;
    const float b = 1.0000001f, c = 1e-7f;
    do {
#pragma unroll
      for (int it = 0; it < 512; ++it) {
        a0 = __builtin_fmaf(a0, b, c); a1 = __builtin_fmaf(a1, b, c);
        a2 = __builtin_fmaf(a2, b, c); a3 = __builtin_fmaf(a3, b, c);
      }
    } while (__hip_atomic_load(p.done, __ATOMIC_RELAXED, __HIP_MEMORY_SCOPE_AGENT) == 0u);
    asm volatile("" :: "v"(a0), "v"(a1), "v"(a2), "v"(a3));
    return;
  }

  const int layer = blk >> 6;
  const int hb    = blk & 63;
  const int w     = tid >> 6;
  const int lane  = tid & 63;
  const int nl    = lane & 15;
  const int quad  = lane >> 4;

  __shared__ float red[8][64 * 33];   // 67.6KB: one dump slab per wave
  __shared__ float csl[Bsz * 16];     // c state [b][hl]
  __shared__ float bsum[64];          // bx+bh  [gate*16+hl]

  if (tid < 64) {
    int r = (tid >> 4) * 1024 + hb * 16 + (tid & 15);
    bsum[tid] = layer ? (p.bx1[r] + p.bh1[r]) : (p.bx0[r] + p.bh0[r]);
  }
  csl[tid] = 0.f;
  __syncthreads();

  // ---- weights: 32 frags = 128 regs per lane, loaded once ----
  const _Float16* wslab = p.wsw + (size_t)(layer * 64 + hb) * 131072;
  f16x8 Wr[32];
#pragma unroll
  for (int kk = 0; kk < 8; ++kk)
#pragma unroll
    for (int m = 0; m < 4; ++m)
      Wr[kk * 4 + m] = *reinterpret_cast<const f16x8*>(
          wslab + (size_t)(((w * 8 + kk) * 4 + m) * 64 + lane) * 8);

  const bool xwave = (layer == 0) && (w < 4);
  const int  kloc  = (w & 3) * 256;   // k-dim slab base for this wave

  for (int s = 0; s < Ssz; ++s) {
    // ---- per-wave flag polls (relaxed): each lane spins on one producer ----
    if (layer == 0) {
      if (xwave) {
        if (s >= 4) {   // h0r slot (s&3) reuse: layer-1 must have finished s-4
          const unsigned* fp = p.f1 + (s & 1) * 64 + lane;
          unsigned need = (unsigned)(s - 3);
          while (__hip_atomic_load(fp, __ATOMIC_RELAXED, __HIP_MEMORY_SCOPE_AGENT) < need) {}
        }
      } else if (s >= 1) {  // own-slab layer-0 producers finished s-1
        const unsigned* fp = p.f0 + ((s - 1) & 3) * 64 + (w & 3) * 16 + nl;
        unsigned need = (unsigned)s;
        while (__hip_atomic_load(fp, __ATOMIC_RELAXED, __HIP_MEMORY_SCOPE_AGENT) < need) {}
      }
    } else {
      if (w < 4) {           // layer-0 slab producers finished s
        const unsigned* fp = p.f0 + (s & 3) * 64 + (w & 3) * 16 + nl;
        unsigned need = (unsigned)(s + 1);
        while (__hip_atomic_load(fp, __ATOMIC_RELAXED, __HIP_MEMORY_SCOPE_AGENT) < need) {}
      } else if (s >= 1) {   // own-slab layer-1 producers finished s-1
        const unsigned* fp = p.f1 + ((s - 1) & 1) * 64 + (w & 3) * 16 + nl;
        unsigned need = (unsigned)s;
        while (__hip_atomic_load(fp, __ATOMIC_RELAXED, __HIP_MEMORY_SCOPE_AGENT) < need) {}
      }
    }

    f32x4 acc[4][2];
#pragma unroll
    for (int m = 0; m < 4; ++m)
#pragma unroll
      for (int nt = 0; nt < 2; ++nt) acc[m][nt] = (f32x4){0.f, 0.f, 0.f, 0.f};

    if (xwave) {
      // ---- x path: normal cached loads, double-buffered ----
      const float* xbase = p.x + (size_t)s * 1024 + kloc;
      f16x8 Bh[2][2], Bl[2][2];
      load_xfrag(xbase + (size_t)nl        * (Ssz * 1024) + quad * 8, Bh[0][0], Bl[0][0]);
      load_xfrag(xbase + (size_t)(nl + 16) * (Ssz * 1024) + quad * 8, Bh[0][1], Bl[0][1]);
#pragma unroll
      for (int kk = 0; kk < 8; ++kk) {
        const int cur = kk & 1, nxt = cur ^ 1;
        if (kk < 7) {
          const int ko = (kk + 1) * 32 + quad * 8;
          load_xfrag(xbase + (size_t)nl        * (Ssz * 1024) + ko, Bh[nxt][0], Bl[nxt][0]);
          load_xfrag(xbase + (size_t)(nl + 16) * (Ssz * 1024) + ko, Bh[nxt][1], Bl[nxt][1]);
        }
#pragma unroll
        for (int m = 0; m < 4; ++m) {
          f16x8 A = Wr[kk * 4 + m];
#pragma unroll
          for (int nt = 0; nt < 2; ++nt) {
            acc[m][nt] = __builtin_amdgcn_mfma_f32_16x16x32_f16(A, Bh[cur][nt], acc[m][nt], 0, 0, 0);
            acc[m][nt] = __builtin_amdgcn_mfma_f32_16x16x32_f16(A, Bl[cur][nt], acc[m][nt], 0, 0, 0);
          }
        }
      }
    } else {
      // ---- h path: acquire fence (invalidate stale L1/L2), then plain
      //      cached 16B fragment loads straight into MFMA operands ----
      __builtin_amdgcn_fence(__ATOMIC_ACQUIRE, "agent");
      const unsigned short* rbase;
      if (layer == 0) rbase = p.h0r + ((s - 1) & 3) * 65536;
      else if (w < 4) rbase = p.h0r + (s & 3) * 65536;
      else            rbase = p.h1r + ((s - 1) & 1) * 65536;
      // frag addr (u16): koct*512 + b*16 + plane*8 + j ; koct = kloc/8 + kk*4 + quad
      const _Float16* fb = (const _Float16*)rbase + ((w & 3) * 32 + quad) * 512 + nl * 16;
#pragma unroll
      for (int kk = 0; kk < 8; ++kk) {
        const _Float16* fp2 = fb + kk * 2048;
        f16x8 Bh0 = *reinterpret_cast<const f16x8*>(fp2);        // b=nl,    hi
        f16x8 Bl0 = *reinterpret_cast<const f16x8*>(fp2 + 8);    // b=nl,    lo
        f16x8 Bh1 = *reinterpret_cast<const f16x8*>(fp2 + 256);  // b=nl+16, hi
        f16x8 Bl1 = *reinterpret_cast<const f16x8*>(fp2 + 264);  // b=nl+16, lo
#pragma unroll
        for (int m = 0; m < 4; ++m) {
          f16x8 A = Wr[kk * 4 + m];
          acc[m][0] = __builtin_amdgcn_mfma_f32_16x16x32_f16(A, Bh0, acc[m][0], 0, 0, 0);
          acc[m][0] = __builtin_amdgcn_mfma_f32_16x16x32_f16(A, Bl0, acc[m][0], 0, 0, 0);
          acc[m][1] = __builtin_amdgcn_mfma_f32_16x16x32_f16(A, Bh1, acc[m][1], 0, 0, 0);
          acc[m][1] = __builtin_amdgcn_mfma_f32_16x16x32_f16(A, Bl1, acc[m][1], 0, 0, 0);
        }
      }
    }

    // ---- reduce: dump all 8 waves, parallel 8-way sum into slab 0 ----
    // D layout: row quad*4+reg = h-local, col nl = batch
#pragma unroll
    for (int m = 0; m < 4; ++m)
#pragma unroll
      for (int nt = 0; nt < 2; ++nt)
#pragma unroll
        for (int r = 0; r < 4; ++r)
          red[w][(m * 16 + quad * 4 + r) * 33 + nt * 16 + nl] = acc[m][nt][r];
    __syncthreads();
#pragma unroll
    for (int j = 0; j < 4; ++j) {
      int idx = tid + j * 512;
      int ad = (idx >> 5) * 33 + (idx & 31);
      float ssum = red[0][ad] + red[1][ad] + red[2][ad] + red[3][ad]
                 + red[4][ad] + red[5][ad] + red[6][ad] + red[7][ad];
      red[0][ad] = ssum;
    }
    __syncthreads();

    // ---- pointwise: tid -> hl = tid&15, b = tid>>4 ----
    {
      int hl = tid & 15, b = tid >> 4;
      float gf = red[0][(0 * 16 + hl) * 33 + b] + bsum[0 * 16 + hl];
      float gi = red[0][(1 * 16 + hl) * 33 + b] + bsum[1 * 16 + hl];
      float gg = red[0][(2 * 16 + hl) * 33 + b] + bsum[2 * 16 + hl];
      float go = red[0][(3 * 16 + hl) * 33 + b] + bsum[3 * 16 + hl];
      float f  = 1.f / (1.f + __expf(-gf));
      float i  = 1.f / (1.f + __expf(-gi));
      float g  = tanhf(gg);
      float o  = 1.f / (1.f + __expf(-go));
      float c  = f * csl[b * 16 + hl] + i * g;
      float hn = o * tanhf(c);
      csl[b * 16 + hl] = c;
      _Float16 hh  = (_Float16)hn;
      _Float16 hlo = (_Float16)(hn - (float)hh);
      unsigned short hbits = __builtin_bit_cast(unsigned short, hh);
      unsigned short lbits = __builtin_bit_cast(unsigned short, hlo);
      int hg   = hb * 16 + hl;
      int koct = hb * 2 + (hl >> 3), jj = hl & 7;
      int fragoff = koct * 512 + b * 16 + jj;
      if (layer == 0) {
        unsigned short* dst = p.h0r + (s & 3) * 65536 + fragoff;
        __hip_atomic_store(dst,     hbits, __ATOMIC_RELAXED, __HIP_MEMORY_SCOPE_AGENT);
        __hip_atomic_store(dst + 8, lbits, __ATOMIC_RELAXED, __HIP_MEMORY_SCOPE_AGENT);
      } else {
        unsigned short* dst = p.h1r + (s & 1) * 65536 + fragoff;
        __hip_atomic_store(dst,     hbits, __ATOMIC_RELAXED, __HIP_MEMORY_SCOPE_AGENT);
        __hip_atomic_store(dst + 8, lbits, __ATOMIC_RELAXED, __HIP_MEMORY_SCOPE_AGENT);
        p.out[(size_t)b * (Ssz * Hsz) + (size_t)s * Hsz + hg] = hn;
      }
      if (s == Ssz - 1) {
        float* tail = p.out + (size_t)Bsz * Ssz * Hsz;
        tail[layer * 32768 + b * 1024 + hg] = hn;            // h_n
        tail[65536 + layer * 32768 + b * 1024 + hg] = c;     // c_n
      }
    }
    __syncthreads();   // drains every wave's agent-scope stores (vmcnt(0) before barrier)
    // single plain agent-scope store; no RMW, ordered after drained h stores
    if (tid == 0) {
      if (layer == 0)
        __hip_atomic_store(p.f0 + (s & 3) * 64 + hb, (unsigned)(s + 1),
                           __ATOMIC_RELAXED, __HIP_MEMORY_SCOPE_AGENT);
      else
        __hip_atomic_store(p.f1 + (s & 1) * 64 + hb, (unsigned)(s + 1),
                           __ATOMIC_RELAXED, __HIP_MEMORY_SCOPE_AGENT);
    }
  }

  // ---- layer-1 blocks signal heaters to exit ----
  if (layer == 1 && tid == 0)
    __hip_atomic_store(p.done, 1u, __ATOMIC_RELAXED, __HIP_MEMORY_SCOPE_AGENT);
}

extern "C" void kernel_launch(void* const* d_in, const int* in_sizes, int n_in,
                              void* d_out, int out_size, void* d_ws, size_t ws_size,
                              hipStream_t stream) {
  char* ws = (char*)d_ws;
  P p;
  p.x   = (const float*)d_in[0];
  p.Wx0 = (const float*)d_in[1]; p.Wh0 = (const float*)d_in[2];
  p.bx0 = (const float*)d_in[3]; p.bh0 = (const float*)d_in[4];
  p.Wx1 = (const float*)d_in[5]; p.Wh1 = (const float*)d_in[6];
  p.bx1 = (const float*)d_in[7]; p.bh1 = (const float*)d_in[8];

  p.h0r  = (unsigned short*)(ws);                 // 4*65536*2B = 512KB
  p.h1r  = (unsigned short*)(ws + 524288);        // 2*65536*2B = 256KB
  p.f0   = (unsigned*)(ws + 786432);              // 4*64*4B = 1KB
  p.f1   = (unsigned*)(ws + 788480);              // 2*64*4B = 512B
  p.done = (unsigned*)(ws + 790528);              // 4B heater exit flag
  p.wsw  = (_Float16*)(ws + 1048576);             // 32MB
  p.out  = (float*)d_out;

  // zero rings + flags + done (ws poisoned 0xAA each call; flags/done MUST
  // start 0, ring slot -1 reads must see h=0)
  hipMemsetAsync(d_ws, 0, 1048576, stream);
  preconv<<<dim3(8192), dim3(256), 0, stream>>>(p);
  lstm_persist<<<dim3(256), dim3(512), 0, stream>>>(p);
}

// Round 4
// 7565.533 us; speedup vs baseline: 1.2006x; 1.1919x over previous
//
#include <hip/hip_runtime.h>
#include <math.h>

#define Bsz 32
#define Ssz 512
#define Hsz 1024
#define SLOTS 16   // ring depth; address reuse period = 16 steps

typedef _Float16 f16x8 __attribute__((ext_vector_type(8)));
typedef float    f32x4 __attribute__((ext_vector_type(4)));
typedef float    f32x8 __attribute__((ext_vector_type(8)));

struct P {
  const float *x, *Wx0, *Wh0, *bx0, *bh0, *Wx1, *Wh1, *bx1, *bh1;
  unsigned short *h0r;    // [16 slot][128 koct][32 b][2 plane][8] f16 frag-layout ring
  unsigned short *h1r;    // [16 slot][...]
  unsigned *f0, *f1;      // per-producer epoch flags: f0[16][64], f1[16][64]
  _Float16 *wsw;          // swizzled fp16 weights [2][64 blk][64 ks][4 m][64 lane][8]
  float *out;
};

// fp32 weights -> fp16, swizzled to exact MFMA A-frag order.
// idx bits: lane[0:5] m[6:7] ks[8:13] blk[14:19] layer[20]
__global__ __launch_bounds__(256) void preconv(P p) {
  unsigned idx   = blockIdx.x * 256 + threadIdx.x;        // < 2^21
  unsigned lane  = idx & 63;
  unsigned m     = (idx >> 6) & 3;
  unsigned ks    = (idx >> 8) & 63;
  unsigned blk   = (idx >> 14) & 63;
  unsigned layer = idx >> 20;
  unsigned hidx  = blk * 16 + (lane & 15);
  unsigned k     = ks * 32 + (lane >> 4) * 8;
  unsigned row   = m * 1024 + hidx;
  const float* src;
  if (layer == 0) src = (k < 1024) ? p.Wx0 + (size_t)row * 1024 + k
                                   : p.Wh0 + (size_t)row * 1024 + (k - 1024);
  else            src = (k < 1024) ? p.Wx1 + (size_t)row * 1024 + k
                                   : p.Wh1 + (size_t)row * 1024 + (k - 1024);
  f32x8 v = *reinterpret_cast<const f32x8*>(src);
  f16x8 h;
#pragma unroll
  for (int j = 0; j < 8; ++j) h[j] = (_Float16)v[j];
  *reinterpret_cast<f16x8*>(p.wsw + (size_t)idx * 8) = h;
}

__device__ inline void load_xfrag(const float* xp, f16x8& Bh, f16x8& Bl) {
  f32x8 v = *reinterpret_cast<const f32x8*>(xp);
#pragma unroll
  for (int j = 0; j < 8; ++j) {
    _Float16 hv = (_Float16)v[j];
    Bh[j] = hv; Bl[j] = (_Float16)(v[j] - (float)hv);
  }
}

// Persistent pipelined LSTM. 128 blocks x 512 thr, weights resident in regs.
// h-ring depth 16, never-stale protocol: acquire fence only every 8 steps ->
// consumers share broadcast lines through per-XCD L2 (8x MALL dedup).
__global__ __launch_bounds__(512, 2) void lstm_persist(P p) {
  const int blk   = blockIdx.x;
  const int layer = blk >> 6;
  const int hb    = blk & 63;
  const int tid   = threadIdx.x;
  const int w     = tid >> 6;
  const int lane  = tid & 63;
  const int nl    = lane & 15;
  const int quad  = lane >> 4;

  __shared__ float red[8][64 * 33];   // 67.6KB: one dump slab per wave
  __shared__ float csl[Bsz * 16];     // c state [b][hl]
  __shared__ float bsum[64];          // bx+bh  [gate*16+hl]

  if (tid < 64) {
    int r = (tid >> 4) * 1024 + hb * 16 + (tid & 15);
    bsum[tid] = layer ? (p.bx1[r] + p.bh1[r]) : (p.bx0[r] + p.bh0[r]);
  }
  csl[tid] = 0.f;
  __syncthreads();

  // ---- weights: 32 frags = 128 regs per lane, loaded once ----
  const _Float16* wslab = p.wsw + (size_t)(layer * 64 + hb) * 131072;
  f16x8 Wr[32];
#pragma unroll
  for (int kk = 0; kk < 8; ++kk)
#pragma unroll
    for (int m = 0; m < 4; ++m)
      Wr[kk * 4 + m] = *reinterpret_cast<const f16x8*>(
          wslab + (size_t)(((w * 8 + kk) * 4 + m) * 64 + lane) * 8);

  const bool xwave = (layer == 0) && (w < 4);
  const int  kloc  = (w & 3) * 256;   // k-dim slab base for this wave

  for (int s = 0; s < Ssz; ++s) {
    // ---- per-wave flag polls (relaxed, throttled): one producer per lane ----
    if (layer == 0) {
      if (xwave) {
        if (s >= 16) {  // h0r slot (s&15) reuse: layer-1 must be done with s-16
          const unsigned* fp = p.f1 + (s & 15) * 64 + lane;   // (s-16)&15 == s&15
          unsigned need = (unsigned)(s - 15);
          while (__hip_atomic_load(fp, __ATOMIC_RELAXED, __HIP_MEMORY_SCOPE_AGENT) < need)
            __builtin_amdgcn_s_sleep(2);
        }
      } else if (s >= 1) {  // own-slab layer-0 producers finished s-1
        const unsigned* fp = p.f0 + ((s - 1) & 15) * 64 + (w & 3) * 16 + nl;
        unsigned need = (unsigned)s;
        while (__hip_atomic_load(fp, __ATOMIC_RELAXED, __HIP_MEMORY_SCOPE_AGENT) < need)
          __builtin_amdgcn_s_sleep(2);
      }
    } else {
      if (w < 4) {           // layer-0 slab producers finished s
        const unsigned* fp = p.f0 + (s & 15) * 64 + (w & 3) * 16 + nl;
        unsigned need = (unsigned)(s + 1);
        while (__hip_atomic_load(fp, __ATOMIC_RELAXED, __HIP_MEMORY_SCOPE_AGENT) < need)
          __builtin_amdgcn_s_sleep(2);
      } else if (s >= 1) {   // own-slab layer-1 producers finished s-1
        const unsigned* fp = p.f1 + ((s - 1) & 15) * 64 + (w & 3) * 16 + nl;
        unsigned need = (unsigned)s;
        while (__hip_atomic_load(fp, __ATOMIC_RELAXED, __HIP_MEMORY_SCOPE_AGENT) < need)
          __builtin_amdgcn_s_sleep(2);
      }
    }

    // ---- periodic acquire: invalidate L1/L2 so ≥16-step-old ring copies die.
    //      Between fences, broadcast lines are shared via per-XCD L2. ----
    if (!xwave && ((s & 7) == 0))
      __builtin_amdgcn_fence(__ATOMIC_ACQUIRE, "agent");

    f32x4 acc[4][2];
#pragma unroll
    for (int m = 0; m < 4; ++m)
#pragma unroll
      for (int nt = 0; nt < 2; ++nt) acc[m][nt] = (f32x4){0.f, 0.f, 0.f, 0.f};

    if (xwave) {
      // ---- x path: normal cached loads, double-buffered ----
      const float* xbase = p.x + (size_t)s * 1024 + kloc;
      f16x8 Bh[2][2], Bl[2][2];
      load_xfrag(xbase + (size_t)nl        * (Ssz * 1024) + quad * 8, Bh[0][0], Bl[0][0]);
      load_xfrag(xbase + (size_t)(nl + 16) * (Ssz * 1024) + quad * 8, Bh[0][1], Bl[0][1]);
#pragma unroll
      for (int kk = 0; kk < 8; ++kk) {
        const int cur = kk & 1, nxt = cur ^ 1;
        if (kk < 7) {
          const int ko = (kk + 1) * 32 + quad * 8;
          load_xfrag(xbase + (size_t)nl        * (Ssz * 1024) + ko, Bh[nxt][0], Bl[nxt][0]);
          load_xfrag(xbase + (size_t)(nl + 16) * (Ssz * 1024) + ko, Bh[nxt][1], Bl[nxt][1]);
        }
#pragma unroll
        for (int m = 0; m < 4; ++m) {
          f16x8 A = Wr[kk * 4 + m];
#pragma unroll
          for (int nt = 0; nt < 2; ++nt) {
            acc[m][nt] = __builtin_amdgcn_mfma_f32_16x16x32_f16(A, Bh[cur][nt], acc[m][nt], 0, 0, 0);
            acc[m][nt] = __builtin_amdgcn_mfma_f32_16x16x32_f16(A, Bl[cur][nt], acc[m][nt], 0, 0, 0);
          }
        }
      }
    } else {
      // ---- h path: plain cached 16B fragment loads (L2-shared per XCD) ----
      const unsigned short* rbase;
      if (layer == 0) rbase = p.h0r + ((s - 1) & 15) * 65536;
      else if (w < 4) rbase = p.h0r + (s & 15) * 65536;
      else            rbase = p.h1r + ((s - 1) & 15) * 65536;
      // frag addr (u16): koct*512 + b*16 + plane*8 + j ; koct = kloc/8 + kk*4 + quad
      const _Float16* fb = (const _Float16*)rbase + ((w & 3) * 32 + quad) * 512 + nl * 16;
#pragma unroll
      for (int kk = 0; kk < 8; ++kk) {
        const _Float16* fp2 = fb + kk * 2048;
        f16x8 Bh0 = *reinterpret_cast<const f16x8*>(fp2);        // b=nl,    hi
        f16x8 Bl0 = *reinterpret_cast<const f16x8*>(fp2 + 8);    // b=nl,    lo
        f16x8 Bh1 = *reinterpret_cast<const f16x8*>(fp2 + 256);  // b=nl+16, hi
        f16x8 Bl1 = *reinterpret_cast<const f16x8*>(fp2 + 264);  // b=nl+16, lo
#pragma unroll
        for (int m = 0; m < 4; ++m) {
          f16x8 A = Wr[kk * 4 + m];
          acc[m][0] = __builtin_amdgcn_mfma_f32_16x16x32_f16(A, Bh0, acc[m][0], 0, 0, 0);
          acc[m][0] = __builtin_amdgcn_mfma_f32_16x16x32_f16(A, Bl0, acc[m][0], 0, 0, 0);
          acc[m][1] = __builtin_amdgcn_mfma_f32_16x16x32_f16(A, Bh1, acc[m][1], 0, 0, 0);
          acc[m][1] = __builtin_amdgcn_mfma_f32_16x16x32_f16(A, Bl1, acc[m][1], 0, 0, 0);
        }
      }
    }

    // ---- reduce: dump all 8 waves, parallel 8-way sum into slab 0 ----
    // D layout: row quad*4+reg = h-local, col nl = batch
#pragma unroll
    for (int m = 0; m < 4; ++m)
#pragma unroll
      for (int nt = 0; nt < 2; ++nt)
#pragma unroll
        for (int r = 0; r < 4; ++r)
          red[w][(m * 16 + quad * 4 + r) * 33 + nt * 16 + nl] = acc[m][nt][r];
    __syncthreads();
#pragma unroll
    for (int j = 0; j < 4; ++j) {
      int idx = tid + j * 512;
      int ad = (idx >> 5) * 33 + (idx & 31);
      float ssum = red[0][ad] + red[1][ad] + red[2][ad] + red[3][ad]
                 + red[4][ad] + red[5][ad] + red[6][ad] + red[7][ad];
      red[0][ad] = ssum;
    }
    __syncthreads();

    // ---- pointwise: tid -> hl = tid&15, b = tid>>4 ----
    {
      int hl = tid & 15, b = tid >> 4;
      float gf = red[0][(0 * 16 + hl) * 33 + b] + bsum[0 * 16 + hl];
      float gi = red[0][(1 * 16 + hl) * 33 + b] + bsum[1 * 16 + hl];
      float gg = red[0][(2 * 16 + hl) * 33 + b] + bsum[2 * 16 + hl];
      float go = red[0][(3 * 16 + hl) * 33 + b] + bsum[3 * 16 + hl];
      float f  = 1.f / (1.f + __expf(-gf));
      float i  = 1.f / (1.f + __expf(-gi));
      float g  = tanhf(gg);
      float o  = 1.f / (1.f + __expf(-go));
      float c  = f * csl[b * 16 + hl] + i * g;
      float hn = o * tanhf(c);
      csl[b * 16 + hl] = c;
      _Float16 hh  = (_Float16)hn;
      _Float16 hlo = (_Float16)(hn - (float)hh);
      unsigned short hbits = __builtin_bit_cast(unsigned short, hh);
      unsigned short lbits = __builtin_bit_cast(unsigned short, hlo);
      int hg   = hb * 16 + hl;
      int koct = hb * 2 + (hl >> 3), jj = hl & 7;
      int fragoff = koct * 512 + b * 16 + jj;
      if (layer == 0) {
        unsigned short* dst = p.h0r + (s & 15) * 65536 + fragoff;
        __hip_atomic_store(dst,     hbits, __ATOMIC_RELAXED, __HIP_MEMORY_SCOPE_AGENT);
        __hip_atomic_store(dst + 8, lbits, __ATOMIC_RELAXED, __HIP_MEMORY_SCOPE_AGENT);
      } else {
        unsigned short* dst = p.h1r + (s & 15) * 65536 + fragoff;
        __hip_atomic_store(dst,     hbits, __ATOMIC_RELAXED, __HIP_MEMORY_SCOPE_AGENT);
        __hip_atomic_store(dst + 8, lbits, __ATOMIC_RELAXED, __HIP_MEMORY_SCOPE_AGENT);
        p.out[(size_t)b * (Ssz * Hsz) + (size_t)s * Hsz + hg] = hn;
      }
      if (s == Ssz - 1) {
        float* tail = p.out + (size_t)Bsz * Ssz * Hsz;
        tail[layer * 32768 + b * 1024 + hg] = hn;            // h_n
        tail[65536 + layer * 32768 + b * 1024 + hg] = c;     // c_n
      }
    }
    __syncthreads();   // drains every wave's agent-scope stores (vmcnt(0) before barrier)
    // single plain agent-scope store; no RMW, ordered after drained h stores
    if (tid == 0) {
      if (layer == 0)
        __hip_atomic_store(p.f0 + (s & 15) * 64 + hb, (unsigned)(s + 1),
                           __ATOMIC_RELAXED, __HIP_MEMORY_SCOPE_AGENT);
      else
        __hip_atomic_store(p.f1 + (s & 15) * 64 + hb, (unsigned)(s + 1),
                           __ATOMIC_RELAXED, __HIP_MEMORY_SCOPE_AGENT);
    }
  }
}

extern "C" void kernel_launch(void* const* d_in, const int* in_sizes, int n_in,
                              void* d_out, int out_size, void* d_ws, size_t ws_size,
                              hipStream_t stream) {
  char* ws = (char*)d_ws;
  P p;
  p.x   = (const float*)d_in[0];
  p.Wx0 = (const float*)d_in[1]; p.Wh0 = (const float*)d_in[2];
  p.bx0 = (const float*)d_in[3]; p.bh0 = (const float*)d_in[4];
  p.Wx1 = (const float*)d_in[5]; p.Wh1 = (const float*)d_in[6];
  p.bx1 = (const float*)d_in[7]; p.bh1 = (const float*)d_in[8];

  p.h0r = (unsigned short*)(ws);                  // 16*65536*2B = 2MB
  p.h1r = (unsigned short*)(ws + 2097152);        // 2MB
  p.f0  = (unsigned*)(ws + 4194304);              // 16*64*4B = 4KB
  p.f1  = (unsigned*)(ws + 4198400);              // 4KB
  p.wsw = (_Float16*)(ws + 8388608);              // 32MB
  p.out = (float*)d_out;

  // zero rings + flags (ws poisoned 0xAA each call; flags MUST start 0,
  // ring slot -1 reads must see h=0)
  hipMemsetAsync(d_ws, 0, 4202496, stream);
  preconv<<<dim3(8192), dim3(256), 0, stream>>>(p);
  lstm_persist<<<dim3(128), dim3(512), 0, stream>>>(p);
}

// Round 5
// 7334.103 us; speedup vs baseline: 1.2385x; 1.0316x over previous
//
#include <hip/hip_runtime.h>
#include <math.h>

#define Bsz 32
#define Ssz 512
#define Hsz 1024
#define SLOTS 16   // ring depth; address reuse period = 16 steps

typedef _Float16 f16x8 __attribute__((ext_vector_type(8)));
typedef float    f32x4 __attribute__((ext_vector_type(4)));
typedef float    f32x8 __attribute__((ext_vector_type(8)));

struct P {
  const float *x, *Wx0, *Wh0, *bx0, *bh0, *Wx1, *Wh1, *bx1, *bh1;
  unsigned short *h0r;    // [16 slot][128 koct][32 b][2 plane][8] f16 frag-layout ring
  unsigned short *h1r;    // [16 slot][...]
  unsigned *f0, *f1;      // per-producer epoch flags: f0[16][64], f1[16][64]
  _Float16 *wsw;          // swizzled fp16 weights [2][64 blk][64 ks][4 m][64 lane][8]
  float *out;
};

// fp32 weights -> fp16, swizzled to exact MFMA A-frag order.
// idx bits: lane[0:5] m[6:7] ks[8:13] blk[14:19] layer[20]
// Weight reads are nontemporal: 128MB read-once must not thrash the MALL,
// which has to stay hot for the rings during the persistent phase.
__global__ __launch_bounds__(256) void preconv(P p) {
  unsigned idx   = blockIdx.x * 256 + threadIdx.x;        // < 2^21
  unsigned lane  = idx & 63;
  unsigned m     = (idx >> 6) & 3;
  unsigned ks    = (idx >> 8) & 63;
  unsigned blk   = (idx >> 14) & 63;
  unsigned layer = idx >> 20;
  unsigned hidx  = blk * 16 + (lane & 15);
  unsigned k     = ks * 32 + (lane >> 4) * 8;
  unsigned row   = m * 1024 + hidx;
  const float* src;
  if (layer == 0) src = (k < 1024) ? p.Wx0 + (size_t)row * 1024 + k
                                   : p.Wh0 + (size_t)row * 1024 + (k - 1024);
  else            src = (k < 1024) ? p.Wx1 + (size_t)row * 1024 + k
                                   : p.Wh1 + (size_t)row * 1024 + (k - 1024);
  f32x8 v = __builtin_nontemporal_load(reinterpret_cast<const f32x8*>(src));
  f16x8 h;
#pragma unroll
  for (int j = 0; j < 8; ++j) h[j] = (_Float16)v[j];
  *reinterpret_cast<f16x8*>(p.wsw + (size_t)idx * 8) = h;
}

__device__ inline void load_xfrag(const float* xp, f16x8& Bh, f16x8& Bl) {
  f32x8 v = *reinterpret_cast<const f32x8*>(xp);   // cached: 64x reuse across blocks
#pragma unroll
  for (int j = 0; j < 8; ++j) {
    _Float16 hv = (_Float16)v[j];
    Bh[j] = hv; Bl[j] = (_Float16)(v[j] - (float)hv);
  }
}

// Persistent pipelined LSTM. 128 blocks x 512 thr, weights resident in regs.
// h-ring depth 16, acquire fence every 8 steps (per-XCD L2 broadcast sharing).
// out stores are NONTEMPORAL so the 128MB stream never evicts rings/x from MALL.
__global__ __launch_bounds__(512, 2) void lstm_persist(P p) {
  const int blk   = blockIdx.x;
  const int layer = blk >> 6;
  const int hb    = blk & 63;
  const int tid   = threadIdx.x;
  const int w     = tid >> 6;
  const int lane  = tid & 63;
  const int nl    = lane & 15;
  const int quad  = lane >> 4;

  __shared__ float red[8][64 * 33];   // 67.6KB: one dump slab per wave
  __shared__ float csl[Bsz * 16];     // c state [b][hl]
  __shared__ float bsum[64];          // bx+bh  [gate*16+hl]

  if (tid < 64) {
    int r = (tid >> 4) * 1024 + hb * 16 + (tid & 15);
    bsum[tid] = layer ? (p.bx1[r] + p.bh1[r]) : (p.bx0[r] + p.bh0[r]);
  }
  csl[tid] = 0.f;
  __syncthreads();

  // ---- weights: 32 frags = 128 regs per lane, loaded once ----
  const _Float16* wslab = p.wsw + (size_t)(layer * 64 + hb) * 131072;
  f16x8 Wr[32];
#pragma unroll
  for (int kk = 0; kk < 8; ++kk)
#pragma unroll
    for (int m = 0; m < 4; ++m)
      Wr[kk * 4 + m] = *reinterpret_cast<const f16x8*>(
          wslab + (size_t)(((w * 8 + kk) * 4 + m) * 64 + lane) * 8);

  const bool xwave = (layer == 0) && (w < 4);
  const int  kloc  = (w & 3) * 256;   // k-dim slab base for this wave

  for (int s = 0; s < Ssz; ++s) {
    // ---- per-wave flag polls (relaxed, throttled): one producer per lane ----
    if (layer == 0) {
      if (xwave) {
        if (s >= 16) {  // h0r slot (s&15) reuse: layer-1 must be done with s-16
          const unsigned* fp = p.f1 + (s & 15) * 64 + lane;   // (s-16)&15 == s&15
          unsigned need = (unsigned)(s - 15);
          while (__hip_atomic_load(fp, __ATOMIC_RELAXED, __HIP_MEMORY_SCOPE_AGENT) < need)
            __builtin_amdgcn_s_sleep(2);
        }
      } else if (s >= 1) {  // own-slab layer-0 producers finished s-1
        const unsigned* fp = p.f0 + ((s - 1) & 15) * 64 + (w & 3) * 16 + nl;
        unsigned need = (unsigned)s;
        while (__hip_atomic_load(fp, __ATOMIC_RELAXED, __HIP_MEMORY_SCOPE_AGENT) < need)
          __builtin_amdgcn_s_sleep(2);
      }
    } else {
      if (w < 4) {           // layer-0 slab producers finished s
        const unsigned* fp = p.f0 + (s & 15) * 64 + (w & 3) * 16 + nl;
        unsigned need = (unsigned)(s + 1);
        while (__hip_atomic_load(fp, __ATOMIC_RELAXED, __HIP_MEMORY_SCOPE_AGENT) < need)
          __builtin_amdgcn_s_sleep(2);
      } else if (s >= 1) {   // own-slab layer-1 producers finished s-1
        const unsigned* fp = p.f1 + ((s - 1) & 15) * 64 + (w & 3) * 16 + nl;
        unsigned need = (unsigned)s;
        while (__hip_atomic_load(fp, __ATOMIC_RELAXED, __HIP_MEMORY_SCOPE_AGENT) < need)
          __builtin_amdgcn_s_sleep(2);
      }
    }

    // ---- periodic acquire: invalidate L1/L2 so ≥16-step-old ring copies die.
    //      Between fences, broadcast lines are shared via per-XCD L2. ----
    if (!xwave && ((s & 7) == 0))
      __builtin_amdgcn_fence(__ATOMIC_ACQUIRE, "agent");

    f32x4 acc[4][2];
#pragma unroll
    for (int m = 0; m < 4; ++m)
#pragma unroll
      for (int nt = 0; nt < 2; ++nt) acc[m][nt] = (f32x4){0.f, 0.f, 0.f, 0.f};

    if (xwave) {
      // ---- x path: normal cached loads, double-buffered ----
      const float* xbase = p.x + (size_t)s * 1024 + kloc;
      f16x8 Bh[2][2], Bl[2][2];
      load_xfrag(xbase + (size_t)nl        * (Ssz * 1024) + quad * 8, Bh[0][0], Bl[0][0]);
      load_xfrag(xbase + (size_t)(nl + 16) * (Ssz * 1024) + quad * 8, Bh[0][1], Bl[0][1]);
#pragma unroll
      for (int kk = 0; kk < 8; ++kk) {
        const int cur = kk & 1, nxt = cur ^ 1;
        if (kk < 7) {
          const int ko = (kk + 1) * 32 + quad * 8;
          load_xfrag(xbase + (size_t)nl        * (Ssz * 1024) + ko, Bh[nxt][0], Bl[nxt][0]);
          load_xfrag(xbase + (size_t)(nl + 16) * (Ssz * 1024) + ko, Bh[nxt][1], Bl[nxt][1]);
        }
#pragma unroll
        for (int m = 0; m < 4; ++m) {
          f16x8 A = Wr[kk * 4 + m];
#pragma unroll
          for (int nt = 0; nt < 2; ++nt) {
            acc[m][nt] = __builtin_amdgcn_mfma_f32_16x16x32_f16(A, Bh[cur][nt], acc[m][nt], 0, 0, 0);
            acc[m][nt] = __builtin_amdgcn_mfma_f32_16x16x32_f16(A, Bl[cur][nt], acc[m][nt], 0, 0, 0);
          }
        }
      }
    } else {
      // ---- h path: plain cached 16B fragment loads (L2-shared per XCD) ----
      const unsigned short* rbase;
      if (layer == 0) rbase = p.h0r + ((s - 1) & 15) * 65536;
      else if (w < 4) rbase = p.h0r + (s & 15) * 65536;
      else            rbase = p.h1r + ((s - 1) & 15) * 65536;
      // frag addr (u16): koct*512 + b*16 + plane*8 + j ; koct = kloc/8 + kk*4 + quad
      const _Float16* fb = (const _Float16*)rbase + ((w & 3) * 32 + quad) * 512 + nl * 16;
#pragma unroll
      for (int kk = 0; kk < 8; ++kk) {
        const _Float16* fp2 = fb + kk * 2048;
        f16x8 Bh0 = *reinterpret_cast<const f16x8*>(fp2);        // b=nl,    hi
        f16x8 Bl0 = *reinterpret_cast<const f16x8*>(fp2 + 8);    // b=nl,    lo
        f16x8 Bh1 = *reinterpret_cast<const f16x8*>(fp2 + 256);  // b=nl+16, hi
        f16x8 Bl1 = *reinterpret_cast<const f16x8*>(fp2 + 264);  // b=nl+16, lo
#pragma unroll
        for (int m = 0; m < 4; ++m) {
          f16x8 A = Wr[kk * 4 + m];
          acc[m][0] = __builtin_amdgcn_mfma_f32_16x16x32_f16(A, Bh0, acc[m][0], 0, 0, 0);
          acc[m][0] = __builtin_amdgcn_mfma_f32_16x16x32_f16(A, Bl0, acc[m][0], 0, 0, 0);
          acc[m][1] = __builtin_amdgcn_mfma_f32_16x16x32_f16(A, Bh1, acc[m][1], 0, 0, 0);
          acc[m][1] = __builtin_amdgcn_mfma_f32_16x16x32_f16(A, Bl1, acc[m][1], 0, 0, 0);
        }
      }
    }

    // ---- reduce: dump all 8 waves, parallel 8-way sum into slab 0 ----
    // D layout: row quad*4+reg = h-local, col nl = batch
#pragma unroll
    for (int m = 0; m < 4; ++m)
#pragma unroll
      for (int nt = 0; nt < 2; ++nt)
#pragma unroll
        for (int r = 0; r < 4; ++r)
          red[w][(m * 16 + quad * 4 + r) * 33 + nt * 16 + nl] = acc[m][nt][r];
    __syncthreads();
#pragma unroll
    for (int j = 0; j < 4; ++j) {
      int idx = tid + j * 512;
      int ad = (idx >> 5) * 33 + (idx & 31);
      float ssum = red[0][ad] + red[1][ad] + red[2][ad] + red[3][ad]
                 + red[4][ad] + red[5][ad] + red[6][ad] + red[7][ad];
      red[0][ad] = ssum;
    }
    __syncthreads();

    // ---- pointwise: tid -> hl = tid&15, b = tid>>4 ----
    {
      int hl = tid & 15, b = tid >> 4;
      float gf = red[0][(0 * 16 + hl) * 33 + b] + bsum[0 * 16 + hl];
      float gi = red[0][(1 * 16 + hl) * 33 + b] + bsum[1 * 16 + hl];
      float gg = red[0][(2 * 16 + hl) * 33 + b] + bsum[2 * 16 + hl];
      float go = red[0][(3 * 16 + hl) * 33 + b] + bsum[3 * 16 + hl];
      float f  = 1.f / (1.f + __expf(-gf));
      float i  = 1.f / (1.f + __expf(-gi));
      float g  = tanhf(gg);
      float o  = 1.f / (1.f + __expf(-go));
      float c  = f * csl[b * 16 + hl] + i * g;
      float hn = o * tanhf(c);
      csl[b * 16 + hl] = c;
      _Float16 hh  = (_Float16)hn;
      _Float16 hlo = (_Float16)(hn - (float)hh);
      unsigned short hbits = __builtin_bit_cast(unsigned short, hh);
      unsigned short lbits = __builtin_bit_cast(unsigned short, hlo);
      int hg   = hb * 16 + hl;
      int koct = hb * 2 + (hl >> 3), jj = hl & 7;
      int fragoff = koct * 512 + b * 16 + jj;
      if (layer == 0) {
        unsigned short* dst = p.h0r + (s & 15) * 65536 + fragoff;
        __hip_atomic_store(dst,     hbits, __ATOMIC_RELAXED, __HIP_MEMORY_SCOPE_AGENT);
        __hip_atomic_store(dst + 8, lbits, __ATOMIC_RELAXED, __HIP_MEMORY_SCOPE_AGENT);
      } else {
        unsigned short* dst = p.h1r + (s & 15) * 65536 + fragoff;
        __hip_atomic_store(dst,     hbits, __ATOMIC_RELAXED, __HIP_MEMORY_SCOPE_AGENT);
        __hip_atomic_store(dst + 8, lbits, __ATOMIC_RELAXED, __HIP_MEMORY_SCOPE_AGENT);
        // streaming output: nontemporal, do NOT allocate in MALL
        __builtin_nontemporal_store(hn, p.out + (size_t)b * (Ssz * Hsz) + (size_t)s * Hsz + hg);
      }
      if (s == Ssz - 1) {
        float* tail = p.out + (size_t)Bsz * Ssz * Hsz;
        __builtin_nontemporal_store(hn, tail + layer * 32768 + b * 1024 + hg);         // h_n
        __builtin_nontemporal_store(c,  tail + 65536 + layer * 32768 + b * 1024 + hg); // c_n
      }
    }
    __syncthreads();   // drains every wave's agent-scope stores (vmcnt(0) before barrier)
    // single plain agent-scope store; no RMW, ordered after drained h stores
    if (tid == 0) {
      if (layer == 0)
        __hip_atomic_store(p.f0 + (s & 15) * 64 + hb, (unsigned)(s + 1),
                           __ATOMIC_RELAXED, __HIP_MEMORY_SCOPE_AGENT);
      else
        __hip_atomic_store(p.f1 + (s & 15) * 64 + hb, (unsigned)(s + 1),
                           __ATOMIC_RELAXED, __HIP_MEMORY_SCOPE_AGENT);
    }
  }
}

extern "C" void kernel_launch(void* const* d_in, const int* in_sizes, int n_in,
                              void* d_out, int out_size, void* d_ws, size_t ws_size,
                              hipStream_t stream) {
  char* ws = (char*)d_ws;
  P p;
  p.x   = (const float*)d_in[0];
  p.Wx0 = (const float*)d_in[1]; p.Wh0 = (const float*)d_in[2];
  p.bx0 = (const float*)d_in[3]; p.bh0 = (const float*)d_in[4];
  p.Wx1 = (const float*)d_in[5]; p.Wh1 = (const float*)d_in[6];
  p.bx1 = (const float*)d_in[7]; p.bh1 = (const float*)d_in[8];

  p.h0r = (unsigned short*)(ws);                  // 16*65536*2B = 2MB
  p.h1r = (unsigned short*)(ws + 2097152);        // 2MB
  p.f0  = (unsigned*)(ws + 4194304);              // 16*64*4B = 4KB
  p.f1  = (unsigned*)(ws + 4198400);              // 4KB
  p.wsw = (_Float16*)(ws + 8388608);              // 32MB
  p.out = (float*)d_out;

  // zero rings + flags (ws poisoned 0xAA each call; flags MUST start 0,
  // ring slot -1 reads must see h=0)
  hipMemsetAsync(d_ws, 0, 4202496, stream);
  preconv<<<dim3(8192), dim3(256), 0, stream>>>(p);
  lstm_persist<<<dim3(128), dim3(512), 0, stream>>>(p);
}